// Round 1
// baseline (1957.488 us; speedup 1.0000x reference)
//
#include <hip/hip_runtime.h>
#include <hip/hip_bf16.h>

#define T_STEPS 512
#define BATCH   4096
#define OBS     64
#define ACT     16
#define HDIM    64

__device__ __forceinline__ float ftanh(float x) {
    // tanh(|x|) = 1 - 2/(exp(2|x|)+1); exact at 0, saturates to 1 (inf-safe)
    float ax = fabsf(x);
    float e  = __expf(2.0f * ax);
    float r  = 1.0f - 2.0f * __builtin_amdgcn_rcpf(e + 1.0f);
    return copysignf(r, x);
}

// ---------------- capture: z1 = tanh(tanh(x@Wc1+bc1)@Wc2+bc2) ----------------
// 64-row tile per block, 256 threads, 4x4 micro-tile per thread.
__global__ __launch_bounds__(256) void capture_kernel(
    const float* __restrict__ x, const float* __restrict__ Wc1,
    const float* __restrict__ bc1, const float* __restrict__ Wc2,
    const float* __restrict__ bc2, float* __restrict__ capt)
{
    __shared__ float sW1[64 * 64];
    __shared__ float sW2[64 * 64];
    __shared__ float sB1[64];
    __shared__ float sB2[64];
    __shared__ float xs[64 * 65];   // [row][k], pad 65 (reused for t1 tile)

    const int tid = threadIdx.x;

    // stage weights (coalesced float4)
    for (int i = tid; i < 1024; i += 256) {
        reinterpret_cast<float4*>(sW1)[i] = reinterpret_cast<const float4*>(Wc1)[i];
        reinterpret_cast<float4*>(sW2)[i] = reinterpret_cast<const float4*>(Wc2)[i];
    }
    if (tid < 64) { sB1[tid] = bc1[tid]; sB2[tid] = bc2[tid]; }

    const long row0 = (long)blockIdx.x * 64;

    // stage x tile [64][64] -> xs (coalesced reads, scalar LDS writes)
    for (int i = tid; i < 1024; i += 256) {
        const int r  = i >> 4;
        const int kc = (i & 15) << 2;
        float4 v = *reinterpret_cast<const float4*>(x + (row0 + r) * 64 + kc);
        float* p = &xs[r * 65 + kc];
        p[0] = v.x; p[1] = v.y; p[2] = v.z; p[3] = v.w;
    }
    __syncthreads();

    const int tx = tid & 15;   // col group (4 cols)
    const int ty = tid >> 4;   // row group (4 rows)

    // ---- layer 1 ----
    float acc[4][4];
    #pragma unroll
    for (int i = 0; i < 4; ++i)
        #pragma unroll
        for (int j = 0; j < 4; ++j) acc[i][j] = sB1[tx * 4 + j];

    #pragma unroll 8
    for (int k = 0; k < 64; ++k) {
        float4 w = *reinterpret_cast<const float4*>(&sW1[k * 64 + tx * 4]);
        float xv[4];
        #pragma unroll
        for (int i = 0; i < 4; ++i) xv[i] = xs[(ty * 4 + i) * 65 + k];
        #pragma unroll
        for (int i = 0; i < 4; ++i) {
            acc[i][0] += xv[i] * w.x;
            acc[i][1] += xv[i] * w.y;
            acc[i][2] += xv[i] * w.z;
            acc[i][3] += xv[i] * w.w;
        }
    }

    float t1[4][4];
    #pragma unroll
    for (int i = 0; i < 4; ++i)
        #pragma unroll
        for (int j = 0; j < 4; ++j) t1[i][j] = ftanh(acc[i][j]);

    __syncthreads();   // everyone done reading xs as x
    #pragma unroll
    for (int i = 0; i < 4; ++i)
        #pragma unroll
        for (int j = 0; j < 4; ++j)
            xs[(ty * 4 + i) * 65 + tx * 4 + j] = t1[i][j];
    __syncthreads();

    // ---- layer 2 ----
    #pragma unroll
    for (int i = 0; i < 4; ++i)
        #pragma unroll
        for (int j = 0; j < 4; ++j) acc[i][j] = sB2[tx * 4 + j];

    #pragma unroll 8
    for (int k = 0; k < 64; ++k) {
        float4 w = *reinterpret_cast<const float4*>(&sW2[k * 64 + tx * 4]);
        float xv[4];
        #pragma unroll
        for (int i = 0; i < 4; ++i) xv[i] = xs[(ty * 4 + i) * 65 + k];
        #pragma unroll
        for (int i = 0; i < 4; ++i) {
            acc[i][0] += xv[i] * w.x;
            acc[i][1] += xv[i] * w.y;
            acc[i][2] += xv[i] * w.z;
            acc[i][3] += xv[i] * w.w;
        }
    }

    // tanh + store (float4 per row)
    #pragma unroll
    for (int i = 0; i < 4; ++i) {
        float4 o;
        o.x = ftanh(acc[i][0]);
        o.y = ftanh(acc[i][1]);
        o.z = ftanh(acc[i][2]);
        o.w = ftanh(acc[i][3]);
        *reinterpret_cast<float4*>(capt + (row0 + ty * 4 + i) * 64 + tx * 4) = o;
    }
}

// ---------------- recurrence: one wave per batch row ----------------
// lane j holds column j of Wp1 (80 regs) and Wp2 (64 regs); h broadcast via LDS.
__global__ __launch_bounds__(64) void recur_kernel(
    const float* __restrict__ h0, const float* __restrict__ g,
    const float* __restrict__ a, const float* __restrict__ Wp1,
    const float* __restrict__ bp1, const float* __restrict__ Wp2,
    const float* __restrict__ bp2, const float* __restrict__ z1,
    float* __restrict__ outs, float* __restrict__ hfin)
{
    __shared__ float sha[80];   // concat(h, a_t)
    __shared__ float st1[64];   // tanh(layer1)

    const int b    = blockIdx.x;
    const int lane = threadIdx.x;

    float w1[80];
    #pragma unroll
    for (int k = 0; k < 80; ++k) w1[k] = Wp1[k * 64 + lane];
    float w2[64];
    #pragma unroll
    for (int k = 0; k < 64; ++k) w2[k] = Wp2[k * 64 + lane];
    const float b1 = bp1[lane];
    const float b2 = bp2[lane];

    float hv = h0[b * 64 + lane];

    for (int t = 0; t < T_STEPS; ++t) {
        const long idx = (long)t * BATCH + b;
        const float gv  = g[idx];                 // uniform broadcast
        const float z1v = z1[idx * 64 + lane];    // coalesced
        sha[lane] = hv;
        if (lane < ACT) sha[64 + lane] = a[idx * ACT + lane];
        __syncthreads();   // sha ready; also guarantees prev-iter st1 reads done

        float a0 = b1, a1 = 0.f, a2 = 0.f, a3 = 0.f;
        #pragma unroll
        for (int k = 0; k < 80; k += 4) {
            a0 += sha[k + 0] * w1[k + 0];
            a1 += sha[k + 1] * w1[k + 1];
            a2 += sha[k + 2] * w1[k + 2];
            a3 += sha[k + 3] * w1[k + 3];
        }
        const float t1v = ftanh((a0 + a1) + (a2 + a3));
        st1[lane] = t1v;
        __syncthreads();   // st1 ready; also guarantees sha reads done

        float c0 = b2, c1 = 0.f, c2 = 0.f, c3 = 0.f;
        #pragma unroll
        for (int k = 0; k < 64; k += 4) {
            c0 += st1[k + 0] * w2[k + 0];
            c1 += st1[k + 1] * w2[k + 1];
            c2 += st1[k + 2] * w2[k + 2];
            c3 += st1[k + 3] * w2[k + 3];
        }
        const float z2 = ftanh((c0 + c1) + (c2 + c3));

        hv = (1.0f - gv) * z1v + gv * z2;
        outs[idx * 64 + lane] = hv;
    }
    hfin[b * 64 + lane] = hv;
}

extern "C" void kernel_launch(void* const* d_in, const int* in_sizes, int n_in,
                              void* d_out, int out_size, void* d_ws, size_t ws_size,
                              hipStream_t stream) {
    const float* x   = (const float*)d_in[0];
    const float* h0  = (const float*)d_in[1];
    const float* g   = (const float*)d_in[2];
    const float* a   = (const float*)d_in[3];
    const float* Wc1 = (const float*)d_in[4];
    const float* bc1 = (const float*)d_in[5];
    const float* Wc2 = (const float*)d_in[6];
    const float* bc2 = (const float*)d_in[7];
    const float* Wp1 = (const float*)d_in[8];
    const float* bp1 = (const float*)d_in[9];
    const float* Wp2 = (const float*)d_in[10];
    const float* bp2 = (const float*)d_in[11];

    float* outs = (float*)d_out;
    float* hfin = outs + (long)T_STEPS * BATCH * HDIM;
    float* capt = hfin + (long)BATCH * HDIM;

    // capture: z1 -> capt region (also consumed by recurrence)
    capture_kernel<<<(T_STEPS * BATCH) / 64, 256, 0, stream>>>(x, Wc1, bc1, Wc2, bc2, capt);
    // recurrence: one wave per batch row
    recur_kernel<<<BATCH, 64, 0, stream>>>(h0, g, a, Wp1, bp1, Wp2, bp2, capt, outs, hfin);
}

// Round 2
// 979.165 us; speedup vs baseline: 1.9991x; 1.9991x over previous
//
#include <hip/hip_runtime.h>
#include <hip/hip_bf16.h>

#define T_STEPS 512
#define BATCH   4096
#define OBS     64
#define ACT     16
#define HDIM    64

typedef short s8v __attribute__((ext_vector_type(8)));   // 8 bf16 (4 VGPR) MFMA A/B frag
typedef float f4v __attribute__((ext_vector_type(4)));   // MFMA C/D frag

__device__ __forceinline__ unsigned short f2bf(float f) {
    // round-to-nearest-even bf16 (values are small/finite here; no NaN handling)
    unsigned u = __builtin_bit_cast(unsigned, f);
    u += 0x7FFFu + ((u >> 16) & 1u);
    return (unsigned short)(u >> 16);
}
__device__ __forceinline__ float bf2f(unsigned short b) {
    return __builtin_bit_cast(float, ((unsigned)b) << 16);
}

__device__ __forceinline__ float ftanh(float x) {
    // tanh(|x|) = 1 - 2/(exp(2|x|)+1); exact at 0, saturates to 1 (inf-safe)
    float ax = fabsf(x);
    float e  = __expf(2.0f * ax);
    float r  = 1.0f - 2.0f * __builtin_amdgcn_rcpf(e + 1.0f);
    return copysignf(r, x);
}

// ---------------- capture: z1 = tanh(tanh(x@Wc1+bc1)@Wc2+bc2) ----------------
// (unchanged from round 1: f32 VALU, ~360us, near its f32 ceiling)
__global__ __launch_bounds__(256) void capture_kernel(
    const float* __restrict__ x, const float* __restrict__ Wc1,
    const float* __restrict__ bc1, const float* __restrict__ Wc2,
    const float* __restrict__ bc2, float* __restrict__ capt)
{
    __shared__ float sW1[64 * 64];
    __shared__ float sW2[64 * 64];
    __shared__ float sB1[64];
    __shared__ float sB2[64];
    __shared__ float xs[64 * 65];

    const int tid = threadIdx.x;

    for (int i = tid; i < 1024; i += 256) {
        reinterpret_cast<float4*>(sW1)[i] = reinterpret_cast<const float4*>(Wc1)[i];
        reinterpret_cast<float4*>(sW2)[i] = reinterpret_cast<const float4*>(Wc2)[i];
    }
    if (tid < 64) { sB1[tid] = bc1[tid]; sB2[tid] = bc2[tid]; }

    const long row0 = (long)blockIdx.x * 64;

    for (int i = tid; i < 1024; i += 256) {
        const int r  = i >> 4;
        const int kc = (i & 15) << 2;
        float4 v = *reinterpret_cast<const float4*>(x + (row0 + r) * 64 + kc);
        float* p = &xs[r * 65 + kc];
        p[0] = v.x; p[1] = v.y; p[2] = v.z; p[3] = v.w;
    }
    __syncthreads();

    const int tx = tid & 15;
    const int ty = tid >> 4;

    float acc[4][4];
    #pragma unroll
    for (int i = 0; i < 4; ++i)
        #pragma unroll
        for (int j = 0; j < 4; ++j) acc[i][j] = sB1[tx * 4 + j];

    #pragma unroll 8
    for (int k = 0; k < 64; ++k) {
        float4 w = *reinterpret_cast<const float4*>(&sW1[k * 64 + tx * 4]);
        float xv[4];
        #pragma unroll
        for (int i = 0; i < 4; ++i) xv[i] = xs[(ty * 4 + i) * 65 + k];
        #pragma unroll
        for (int i = 0; i < 4; ++i) {
            acc[i][0] += xv[i] * w.x;
            acc[i][1] += xv[i] * w.y;
            acc[i][2] += xv[i] * w.z;
            acc[i][3] += xv[i] * w.w;
        }
    }

    float t1[4][4];
    #pragma unroll
    for (int i = 0; i < 4; ++i)
        #pragma unroll
        for (int j = 0; j < 4; ++j) t1[i][j] = ftanh(acc[i][j]);

    __syncthreads();
    #pragma unroll
    for (int i = 0; i < 4; ++i)
        #pragma unroll
        for (int j = 0; j < 4; ++j)
            xs[(ty * 4 + i) * 65 + tx * 4 + j] = t1[i][j];
    __syncthreads();

    #pragma unroll
    for (int i = 0; i < 4; ++i)
        #pragma unroll
        for (int j = 0; j < 4; ++j) acc[i][j] = sB2[tx * 4 + j];

    #pragma unroll 8
    for (int k = 0; k < 64; ++k) {
        float4 w = *reinterpret_cast<const float4*>(&sW2[k * 64 + tx * 4]);
        float xv[4];
        #pragma unroll
        for (int i = 0; i < 4; ++i) xv[i] = xs[(ty * 4 + i) * 65 + k];
        #pragma unroll
        for (int i = 0; i < 4; ++i) {
            acc[i][0] += xv[i] * w.x;
            acc[i][1] += xv[i] * w.y;
            acc[i][2] += xv[i] * w.z;
            acc[i][3] += xv[i] * w.w;
        }
    }

    #pragma unroll
    for (int i = 0; i < 4; ++i) {
        float4 o;
        o.x = ftanh(acc[i][0]);
        o.y = ftanh(acc[i][1]);
        o.z = ftanh(acc[i][2]);
        o.w = ftanh(acc[i][3]);
        *reinterpret_cast<float4*>(capt + (row0 + ty * 4 + i) * 64 + tx * 4) = o;
    }
}

// ---------------- recurrence: MFMA, 16 batch rows per block, 4 waves ----------------
// Wave w computes output cols [16w,16w+16). Split-bf16 (hi+lo) on activations AND
// weights -> ~f32 accuracy. Assumed gfx950 16x16x32 fragment maps:
//   A: row = lane&15, k = (lane>>4)*8 + i   (8 contiguous bf16 -> ds_read_b128)
//   B: col = lane&15, k = (lane>>4)*8 + i
//   D: col = lane&15, row = (lane>>4)*4 + r   [guide m89/m91 verified]
// ha LDS row: [h_hi 0..63 | h_lo 64..127 | a_hi 128..143 | a_lo 144..159], stride 168
// t1 LDS row: [hi 0..63 | lo 64..127], stride 136  (both strides -> 2-way bank max)
__global__ __launch_bounds__(256) void recur_mfma(
    const float* __restrict__ h0, const float* __restrict__ g,
    const float* __restrict__ a, const float* __restrict__ Wp1,
    const float* __restrict__ bp1, const float* __restrict__ Wp2,
    const float* __restrict__ bp2, const float* __restrict__ z1,
    float* __restrict__ outs, float* __restrict__ hfin)
{
    __shared__ short ha[16 * 168];
    __shared__ short t1s[16 * 136];

    const int tid   = threadIdx.x;
    const int l     = tid & 63;
    const int w     = tid >> 6;
    const int n     = (w << 4) | (l & 15);     // output column
    const int row_l = l & 15;                  // A-frag row
    const int rgrp  = (l >> 4) << 2;           // D rows rgrp..rgrp+3
    const int kb    = (l >> 4) << 3;           // A/B-frag k base
    const int b0    = blockIdx.x << 4;         // batch slice

    // ---- B-fragments (weights, hi/lo split) preloaded to registers ----
    s8v B1h0, B1h1, B1l0, B1l1, B1a0, B1a1, B2h0, B2h1, B2l0, B2l1;
    #pragma unroll
    for (int i = 0; i < 8; ++i) {
        const int c0 = kb + i, c1 = 32 + kb + i;
        float w1a = Wp1[c0 * 64 + n], w1b = Wp1[c1 * 64 + n];
        unsigned short h1a = f2bf(w1a), h1b = f2bf(w1b);
        B1h0[i] = (short)h1a; B1l0[i] = (short)f2bf(w1a - bf2f(h1a));
        B1h1[i] = (short)h1b; B1l1[i] = (short)f2bf(w1b - bf2f(h1b));
        float w2a = Wp2[c0 * 64 + n], w2b = Wp2[c1 * 64 + n];
        unsigned short h2a = f2bf(w2a), h2b = f2bf(w2b);
        B2h0[i] = (short)h2a; B2l0[i] = (short)f2bf(w2a - bf2f(h2a));
        B2h1[i] = (short)h2b; B2l1[i] = (short)f2bf(w2b - bf2f(h2b));
        const int ca = 64 + ((kb + i) & 15);   // a-part rows of Wp1, stacked twice
        float wa = Wp1[ca * 64 + n];
        unsigned short hA = f2bf(wa);
        B1a0[i] = (short)hA; B1a1[i] = (short)f2bf(wa - bf2f(hA));
    }
    const float b1 = bp1[n], b2 = bp2[n];

    // ---- stage h0 and a[0] into ha ----
    for (int idx = tid; idx < 1024; idx += 256) {
        const int row = idx >> 6, c = idx & 63;
        float v = h0[(b0 + row) * 64 + c];
        unsigned short hi = f2bf(v);
        ha[row * 168 + c]      = (short)hi;
        ha[row * 168 + 64 + c] = (short)f2bf(v - bf2f(hi));
    }
    {
        const int row = tid >> 4, j = tid & 15;
        float v = a[(long)(b0 + row) * ACT + j];
        unsigned short hi = f2bf(v);
        ha[row * 168 + 128 + j] = (short)hi;
        ha[row * 168 + 144 + j] = (short)f2bf(v - bf2f(hi));
    }

    // ---- prefetch z1/g for t=0 ----
    float z1c[4], gc[4];
    #pragma unroll
    for (int r = 0; r < 4; ++r) {
        const long b = b0 + rgrp + r;
        z1c[r] = z1[b * 64 + n];
        gc[r]  = g[b];
    }
    __syncthreads();   // ha ready

    float hlast[4];
    for (int t = 0; t < T_STEPS; ++t) {
        // ---- layer 1: (h_hi+h_lo)(W1_hi+W1_lo) + (a_hi+a_lo)(W1a_hi+W1a_lo) ----
        const short* har = &ha[row_l * 168];
        s8v af0 = *reinterpret_cast<const s8v*>(har + kb);
        s8v af1 = *reinterpret_cast<const s8v*>(har + 32 + kb);
        s8v af2 = *reinterpret_cast<const s8v*>(har + 64 + kb);
        s8v af3 = *reinterpret_cast<const s8v*>(har + 96 + kb);
        s8v afa = *reinterpret_cast<const s8v*>(har + 128 + kb);
        f4v ae = {b1, b1, b1, b1};
        f4v ao = {0.f, 0.f, 0.f, 0.f};
        ae = __builtin_amdgcn_mfma_f32_16x16x32_bf16(af0, B1h0, ae, 0, 0, 0);
        ao = __builtin_amdgcn_mfma_f32_16x16x32_bf16(af1, B1h1, ao, 0, 0, 0);
        ae = __builtin_amdgcn_mfma_f32_16x16x32_bf16(af2, B1h0, ae, 0, 0, 0);  // h_lo * W1_hi
        ao = __builtin_amdgcn_mfma_f32_16x16x32_bf16(af3, B1h1, ao, 0, 0, 0);
        ae = __builtin_amdgcn_mfma_f32_16x16x32_bf16(af0, B1l0, ae, 0, 0, 0);  // h_hi * W1_lo
        ao = __builtin_amdgcn_mfma_f32_16x16x32_bf16(af1, B1l1, ao, 0, 0, 0);
        ae = __builtin_amdgcn_mfma_f32_16x16x32_bf16(afa, B1a0, ae, 0, 0, 0);  // a * W1a_hi
        ao = __builtin_amdgcn_mfma_f32_16x16x32_bf16(afa, B1a1, ao, 0, 0, 0);  // a * W1a_lo

        // prefetch a[t+1] early (hide HBM latency under layer1+layer2)
        float a_next = 0.f;
        if (t < T_STEPS - 1) {
            const int row = tid >> 4, j = tid & 15;
            a_next = a[((long)(t + 1) * BATCH + b0 + row) * ACT + j];
        }

        // t1 = tanh(L1), split hi/lo -> LDS
        #pragma unroll
        for (int r = 0; r < 4; ++r) {
            float v = ftanh(ae[r] + ao[r]);
            unsigned short hi = f2bf(v);
            t1s[(rgrp + r) * 136 + n]      = (short)hi;
            t1s[(rgrp + r) * 136 + 64 + n] = (short)f2bf(v - bf2f(hi));
        }
        __syncthreads();   // t1 ready (also: everyone past ha reads)

        // ---- layer 2: (t1_hi+t1_lo)(W2_hi) + (t1_hi+t1_lo? hi-part)(W2_lo) ----
        const short* t1r = &t1s[row_l * 136];
        s8v bf0 = *reinterpret_cast<const s8v*>(t1r + kb);
        s8v bf1 = *reinterpret_cast<const s8v*>(t1r + 32 + kb);
        s8v bf2_ = *reinterpret_cast<const s8v*>(t1r + 64 + kb);
        s8v bf3 = *reinterpret_cast<const s8v*>(t1r + 96 + kb);
        f4v ce = {b2, b2, b2, b2};
        f4v co = {0.f, 0.f, 0.f, 0.f};
        ce = __builtin_amdgcn_mfma_f32_16x16x32_bf16(bf0, B2h0, ce, 0, 0, 0);
        co = __builtin_amdgcn_mfma_f32_16x16x32_bf16(bf1, B2h1, co, 0, 0, 0);
        ce = __builtin_amdgcn_mfma_f32_16x16x32_bf16(bf2_, B2h0, ce, 0, 0, 0); // t1_lo * W2_hi
        co = __builtin_amdgcn_mfma_f32_16x16x32_bf16(bf3, B2h1, co, 0, 0, 0);
        ce = __builtin_amdgcn_mfma_f32_16x16x32_bf16(bf0, B2l0, ce, 0, 0, 0);  // t1_hi * W2_lo
        co = __builtin_amdgcn_mfma_f32_16x16x32_bf16(bf1, B2l1, co, 0, 0, 0);

        // ---- blend + store + write h back into ha (after barrier: safe) ----
        #pragma unroll
        for (int r = 0; r < 4; ++r) {
            float z2 = ftanh(ce[r] + co[r]);
            float gv = gc[r];
            float hv = (1.0f - gv) * z1c[r] + gv * z2;
            hlast[r] = hv;
            outs[((long)t * BATCH + b0 + rgrp + r) * 64 + n] = hv;
            unsigned short hi = f2bf(hv);
            ha[(rgrp + r) * 168 + n]      = (short)hi;
            ha[(rgrp + r) * 168 + 64 + n] = (short)f2bf(hv - bf2f(hi));
        }

        if (t < T_STEPS - 1) {
            // stage a[t+1] (reads of a[t] finished before prior barrier)
            const int row = tid >> 4, j = tid & 15;
            unsigned short hi = f2bf(a_next);
            ha[row * 168 + 128 + j] = (short)hi;
            ha[row * 168 + 144 + j] = (short)f2bf(a_next - bf2f(hi));
            // prefetch z1/g for t+1 (consumed after next step's layer2)
            const int tn = t + 1;
            #pragma unroll
            for (int r = 0; r < 4; ++r) {
                const long b = b0 + rgrp + r;
                z1c[r] = z1[((long)tn * BATCH + b) * 64 + n];
                gc[r]  = g[(long)tn * BATCH + b];
            }
        }
        __syncthreads();   // ha (h + a) ready for next step
    }

    #pragma unroll
    for (int r = 0; r < 4; ++r)
        hfin[(b0 + rgrp + r) * 64 + n] = hlast[r];
}

extern "C" void kernel_launch(void* const* d_in, const int* in_sizes, int n_in,
                              void* d_out, int out_size, void* d_ws, size_t ws_size,
                              hipStream_t stream) {
    const float* x   = (const float*)d_in[0];
    const float* h0  = (const float*)d_in[1];
    const float* g   = (const float*)d_in[2];
    const float* a   = (const float*)d_in[3];
    const float* Wc1 = (const float*)d_in[4];
    const float* bc1 = (const float*)d_in[5];
    const float* Wc2 = (const float*)d_in[6];
    const float* bc2 = (const float*)d_in[7];
    const float* Wp1 = (const float*)d_in[8];
    const float* bp1 = (const float*)d_in[9];
    const float* Wp2 = (const float*)d_in[10];
    const float* bp2 = (const float*)d_in[11];

    float* outs = (float*)d_out;
    float* hfin = outs + (long)T_STEPS * BATCH * HDIM;
    float* capt = hfin + (long)BATCH * HDIM;

    capture_kernel<<<(T_STEPS * BATCH) / 64, 256, 0, stream>>>(x, Wc1, bc1, Wc2, bc2, capt);
    recur_mfma<<<BATCH / 16, 256, 0, stream>>>(h0, g, a, Wp1, bp1, Wp2, bp2, capt, outs, hfin);
}

// Round 3
// 854.755 us; speedup vs baseline: 2.2901x; 1.1456x over previous
//
#include <hip/hip_runtime.h>
#include <hip/hip_bf16.h>

#define T_STEPS 512
#define BATCH   4096
#define OBS     64
#define ACT     16
#define HDIM    64

typedef short s8v __attribute__((ext_vector_type(8)));   // 8 bf16 (4 VGPR) MFMA A/B frag
typedef float f4v __attribute__((ext_vector_type(4)));   // MFMA C/D frag

__device__ __forceinline__ unsigned short f2bf(float f) {
    unsigned u = __builtin_bit_cast(unsigned, f);
    u += 0x7FFFu + ((u >> 16) & 1u);
    return (unsigned short)(u >> 16);
}
__device__ __forceinline__ float bf2f(unsigned short b) {
    return __builtin_bit_cast(float, ((unsigned)b) << 16);
}
__device__ __forceinline__ float ftanh(float x) {
    float ax = fabsf(x);
    float e  = __expf(2.0f * ax);
    float r  = 1.0f - 2.0f * __builtin_amdgcn_rcpf(e + 1.0f);
    return copysignf(r, x);
}

// raw barrier: lgkmcnt drain only (LDS hazards). NO vmcnt drain -> global
// prefetches/stores stay in flight across the barrier (the round-2 stall).
#define BAR() do { \
    asm volatile("s_waitcnt lgkmcnt(0)" ::: "memory"); \
    __builtin_amdgcn_s_barrier(); \
    asm volatile("" ::: "memory"); \
} while (0)

// ---------------- capture: z1 = tanh(tanh(x@Wc1+bc1)@Wc2+bc2), MFMA ----------------
// 4 waves/block, each wave an independent 16-row tile (no inter-wave sync).
// Split-bf16: x_hi*W_hi + x_lo*W_hi + x_hi*W_lo. t1 relayout via per-wave LDS.
__global__ __launch_bounds__(256, 2) void capture_mfma(
    const float* __restrict__ x, const float* __restrict__ Wc1,
    const float* __restrict__ bc1, const float* __restrict__ Wc2,
    const float* __restrict__ bc2, float* __restrict__ capt)
{
    __shared__ short t1sh[4][16 * 152];   // per wave: [row][ch hi 0..63 | ch lo 64..127]

    const int tid = threadIdx.x;
    const int w   = tid >> 6;
    const int l   = tid & 63;
    const int c   = l & 15;        // A row / D col (within tile)
    const int q   = l >> 4;        // k-group / D row-group
    const long row0 = (long)blockIdx.x * 64 + w * 16;

    // ---- weight B-frags (hi/lo) ----
    s8v W1h[4][2], W1l[4][2], W2h[4][2], W2l[4][2];
    float bc1v[4], bc2v[4];
    #pragma unroll
    for (int n = 0; n < 4; ++n) {
        bc1v[n] = bc1[n * 16 + c];
        bc2v[n] = bc2[n * 16 + c];
        #pragma unroll
        for (int kin = 0; kin < 2; ++kin) {
            #pragma unroll
            for (int i = 0; i < 8; ++i) {
                const int k = kin * 32 + q * 8 + i;
                float v1 = Wc1[k * 64 + n * 16 + c];
                unsigned short h1 = f2bf(v1);
                W1h[n][kin][i] = (short)h1;
                W1l[n][kin][i] = (short)f2bf(v1 - bf2f(h1));
                float v2 = Wc2[k * 64 + n * 16 + c];
                unsigned short h2 = f2bf(v2);
                W2h[n][kin][i] = (short)h2;
                W2l[n][kin][i] = (short)f2bf(v2 - bf2f(h2));
            }
        }
    }

    // ---- x A-frags (hi/lo), 16 floats/lane ----
    const float* xr = x + (row0 + c) * 64 + q * 8;
    float4 xa = *reinterpret_cast<const float4*>(xr);
    float4 xb = *reinterpret_cast<const float4*>(xr + 4);
    float4 xc = *reinterpret_cast<const float4*>(xr + 32);
    float4 xd = *reinterpret_cast<const float4*>(xr + 36);
    float xf[16] = {xa.x, xa.y, xa.z, xa.w, xb.x, xb.y, xb.z, xb.w,
                    xc.x, xc.y, xc.z, xc.w, xd.x, xd.y, xd.z, xd.w};
    s8v xh[2], xl[2];
    #pragma unroll
    for (int kin = 0; kin < 2; ++kin)
        #pragma unroll
        for (int i = 0; i < 8; ++i) {
            float v = xf[kin * 8 + i];
            unsigned short h = f2bf(v);
            xh[kin][i] = (short)h;
            xl[kin][i] = (short)f2bf(v - bf2f(h));
        }

    // ---- layer 1 ----
    short* myt1 = t1sh[w];
    #pragma unroll
    for (int n = 0; n < 4; ++n) {
        f4v u = {bc1v[n], bc1v[n], bc1v[n], bc1v[n]};
        f4v v = {0.f, 0.f, 0.f, 0.f};
        u = __builtin_amdgcn_mfma_f32_16x16x32_bf16(xh[0], W1h[n][0], u, 0, 0, 0);
        v = __builtin_amdgcn_mfma_f32_16x16x32_bf16(xh[1], W1h[n][1], v, 0, 0, 0);
        u = __builtin_amdgcn_mfma_f32_16x16x32_bf16(xl[0], W1h[n][0], u, 0, 0, 0);
        v = __builtin_amdgcn_mfma_f32_16x16x32_bf16(xl[1], W1h[n][1], v, 0, 0, 0);
        u = __builtin_amdgcn_mfma_f32_16x16x32_bf16(xh[0], W1l[n][0], u, 0, 0, 0);
        v = __builtin_amdgcn_mfma_f32_16x16x32_bf16(xh[1], W1l[n][1], v, 0, 0, 0);
        #pragma unroll
        for (int r = 0; r < 4; ++r) {
            float tv = ftanh(u[r] + v[r]);
            unsigned short hi = f2bf(tv);
            myt1[(4 * q + r) * 152 + n * 16 + c]      = (short)hi;
            myt1[(4 * q + r) * 152 + 64 + n * 16 + c] = (short)f2bf(tv - bf2f(hi));
        }
    }

    asm volatile("s_waitcnt lgkmcnt(0)" ::: "memory");   // same-wave LDS RAW

    // ---- layer 2 ----
    const short* tr = &myt1[c * 152];
    s8v t1h0 = *reinterpret_cast<const s8v*>(tr + q * 8);
    s8v t1h1 = *reinterpret_cast<const s8v*>(tr + 32 + q * 8);
    s8v t1l0 = *reinterpret_cast<const s8v*>(tr + 64 + q * 8);
    s8v t1l1 = *reinterpret_cast<const s8v*>(tr + 96 + q * 8);

    #pragma unroll
    for (int n = 0; n < 4; ++n) {
        f4v u = {bc2v[n], bc2v[n], bc2v[n], bc2v[n]};
        f4v v = {0.f, 0.f, 0.f, 0.f};
        u = __builtin_amdgcn_mfma_f32_16x16x32_bf16(t1h0, W2h[n][0], u, 0, 0, 0);
        v = __builtin_amdgcn_mfma_f32_16x16x32_bf16(t1h1, W2h[n][1], v, 0, 0, 0);
        u = __builtin_amdgcn_mfma_f32_16x16x32_bf16(t1l0, W2h[n][0], u, 0, 0, 0);
        v = __builtin_amdgcn_mfma_f32_16x16x32_bf16(t1l1, W2h[n][1], v, 0, 0, 0);
        u = __builtin_amdgcn_mfma_f32_16x16x32_bf16(t1h0, W2l[n][0], u, 0, 0, 0);
        v = __builtin_amdgcn_mfma_f32_16x16x32_bf16(t1h1, W2l[n][1], v, 0, 0, 0);
        #pragma unroll
        for (int r = 0; r < 4; ++r)
            capt[(row0 + 4 * q + r) * 64 + n * 16 + c] = ftanh(u[r] + v[r]);
    }
}

// ---------------- recurrence: MFMA, raw barriers, depth-2 prefetch ----------------
__global__ __launch_bounds__(256) void recur_mfma(
    const float* __restrict__ h0, const float* __restrict__ g,
    const float* __restrict__ a, const float* __restrict__ Wp1,
    const float* __restrict__ bp1, const float* __restrict__ Wp2,
    const float* __restrict__ bp2, const float* __restrict__ z1,
    float* __restrict__ outs, float* __restrict__ hfin)
{
    __shared__ short ha[16 * 168];    // [h_hi 0..63 | h_lo 64..127 | a_hi 128..143 | a_lo 144..159]
    __shared__ short t1s[16 * 152];   // [hi 0..63 | lo 64..127]

    const int tid   = threadIdx.x;
    const int l     = tid & 63;
    const int w     = tid >> 6;
    const int n     = (w << 4) | (l & 15);
    const int row_l = l & 15;
    const int rgrp  = (l >> 4) << 2;
    const int kb    = (l >> 4) << 3;
    const int b0    = blockIdx.x << 4;
    const int arow  = tid >> 4, acol = tid & 15;

    s8v B1h0, B1h1, B1l0, B1l1, B1a0, B1a1, B2h0, B2h1, B2l0, B2l1;
    #pragma unroll
    for (int i = 0; i < 8; ++i) {
        const int c0 = kb + i, c1 = 32 + kb + i;
        float w1a = Wp1[c0 * 64 + n], w1b = Wp1[c1 * 64 + n];
        unsigned short h1a = f2bf(w1a), h1b = f2bf(w1b);
        B1h0[i] = (short)h1a; B1l0[i] = (short)f2bf(w1a - bf2f(h1a));
        B1h1[i] = (short)h1b; B1l1[i] = (short)f2bf(w1b - bf2f(h1b));
        float w2a = Wp2[c0 * 64 + n], w2b = Wp2[c1 * 64 + n];
        unsigned short h2a = f2bf(w2a), h2b = f2bf(w2b);
        B2h0[i] = (short)h2a; B2l0[i] = (short)f2bf(w2a - bf2f(h2a));
        B2h1[i] = (short)h2b; B2l1[i] = (short)f2bf(w2b - bf2f(h2b));
        const int ca = 64 + ((kb + i) & 15);
        float wa = Wp1[ca * 64 + n];
        unsigned short hA = f2bf(wa);
        B1a0[i] = (short)hA; B1a1[i] = (short)f2bf(wa - bf2f(hA));
    }
    const float b1 = bp1[n], b2 = bp2[n];

    // stage h0, a[0]
    for (int idx = tid; idx < 1024; idx += 256) {
        const int row = idx >> 6, cc = idx & 63;
        float v = h0[(b0 + row) * 64 + cc];
        unsigned short hi = f2bf(v);
        ha[row * 168 + cc]      = (short)hi;
        ha[row * 168 + 64 + cc] = (short)f2bf(v - bf2f(hi));
    }
    {
        float v = a[(long)(b0 + arow) * ACT + acol];
        unsigned short hi = f2bf(v);
        ha[arow * 168 + 128 + acol] = (short)hi;
        ha[arow * 168 + 144 + acol] = (short)f2bf(v - bf2f(hi));
    }

    // t=0 consumables + a[1] (written to LDS at end of step 0)
    float zA[4], gA[4], zB[4], gB[4];
    #pragma unroll
    for (int r = 0; r < 4; ++r) {
        const long bb = b0 + rgrp + r;
        zA[r] = z1[bb * 64 + n];
        gA[r] = g[bb];
    }
    float aA = 0.f, aB = a[((long)1 * BATCH + b0 + arow) * ACT + acol];

    __syncthreads();   // one-time full drain

    float hlast[4];

#define RSTEP(tt, z1C, gC, z1N, gN, aISS, aWR) do {                               \
    const int _t   = (tt);                                                        \
    const int _tp1 = (_t + 1 < T_STEPS) ? _t + 1 : T_STEPS - 1;                   \
    const int _tp2 = (_t + 2 < T_STEPS) ? _t + 2 : T_STEPS - 1;                   \
    _Pragma("unroll")                                                             \
    for (int r = 0; r < 4; ++r) {                                                 \
        const long bb = (long)_tp1 * BATCH + b0 + rgrp + r;                       \
        z1N[r] = z1[bb * 64 + n];                                                 \
        gN[r]  = g[bb];                                                           \
    }                                                                             \
    aISS = a[((long)_tp2 * BATCH + b0 + arow) * ACT + acol];                      \
    const short* har = &ha[row_l * 168];                                          \
    s8v af0 = *reinterpret_cast<const s8v*>(har + kb);                            \
    s8v af1 = *reinterpret_cast<const s8v*>(har + 32 + kb);                       \
    s8v af2 = *reinterpret_cast<const s8v*>(har + 64 + kb);                       \
    s8v af3 = *reinterpret_cast<const s8v*>(har + 96 + kb);                       \
    s8v afa = *reinterpret_cast<const s8v*>(har + 128 + kb);                      \
    f4v p0 = {b1, b1, b1, b1};                                                    \
    f4v p1 = {0.f, 0.f, 0.f, 0.f}, p2 = p1, p3 = p1;                              \
    p0 = __builtin_amdgcn_mfma_f32_16x16x32_bf16(af0, B1h0, p0, 0, 0, 0);         \
    p1 = __builtin_amdgcn_mfma_f32_16x16x32_bf16(af1, B1h1, p1, 0, 0, 0);         \
    p2 = __builtin_amdgcn_mfma_f32_16x16x32_bf16(af2, B1h0, p2, 0, 0, 0);         \
    p3 = __builtin_amdgcn_mfma_f32_16x16x32_bf16(af3, B1h1, p3, 0, 0, 0);         \
    p0 = __builtin_amdgcn_mfma_f32_16x16x32_bf16(af0, B1l0, p0, 0, 0, 0);         \
    p1 = __builtin_amdgcn_mfma_f32_16x16x32_bf16(af1, B1l1, p1, 0, 0, 0);         \
    p2 = __builtin_amdgcn_mfma_f32_16x16x32_bf16(afa, B1a0, p2, 0, 0, 0);         \
    p3 = __builtin_amdgcn_mfma_f32_16x16x32_bf16(afa, B1a1, p3, 0, 0, 0);         \
    _Pragma("unroll")                                                             \
    for (int r = 0; r < 4; ++r) {                                                 \
        float tv = ftanh((p0[r] + p1[r]) + (p2[r] + p3[r]));                      \
        unsigned short hi = f2bf(tv);                                             \
        t1s[(rgrp + r) * 152 + n]      = (short)hi;                               \
        t1s[(rgrp + r) * 152 + 64 + n] = (short)f2bf(tv - bf2f(hi));              \
    }                                                                             \
    BAR();                                                                        \
    const short* t1r = &t1s[row_l * 152];                                         \
    s8v bq0 = *reinterpret_cast<const s8v*>(t1r + kb);                            \
    s8v bq1 = *reinterpret_cast<const s8v*>(t1r + 32 + kb);                       \
    s8v bq2 = *reinterpret_cast<const s8v*>(t1r + 64 + kb);                       \
    s8v bq3 = *reinterpret_cast<const s8v*>(t1r + 96 + kb);                       \
    f4v c0 = {b2, b2, b2, b2};                                                    \
    f4v c1 = {0.f, 0.f, 0.f, 0.f}, c2 = c1, c3 = c1;                              \
    c0 = __builtin_amdgcn_mfma_f32_16x16x32_bf16(bq0, B2h0, c0, 0, 0, 0);         \
    c1 = __builtin_amdgcn_mfma_f32_16x16x32_bf16(bq1, B2h1, c1, 0, 0, 0);         \
    c2 = __builtin_amdgcn_mfma_f32_16x16x32_bf16(bq2, B2h0, c2, 0, 0, 0);         \
    c3 = __builtin_amdgcn_mfma_f32_16x16x32_bf16(bq3, B2h1, c3, 0, 0, 0);         \
    c0 = __builtin_amdgcn_mfma_f32_16x16x32_bf16(bq0, B2l0, c0, 0, 0, 0);         \
    c1 = __builtin_amdgcn_mfma_f32_16x16x32_bf16(bq1, B2l1, c1, 0, 0, 0);         \
    _Pragma("unroll")                                                             \
    for (int r = 0; r < 4; ++r) {                                                 \
        float z2 = ftanh((c0[r] + c1[r]) + (c2[r] + c3[r]));                      \
        float hv = fmaf(gC[r], z2 - z1C[r], z1C[r]);                              \
        hlast[r] = hv;                                                            \
        outs[((long)_t * BATCH + b0 + rgrp + r) * 64 + n] = hv;                   \
        unsigned short hi = f2bf(hv);                                             \
        ha[(rgrp + r) * 168 + n]      = (short)hi;                                \
        ha[(rgrp + r) * 168 + 64 + n] = (short)f2bf(hv - bf2f(hi));               \
    }                                                                             \
    {                                                                             \
        unsigned short hi = f2bf(aWR);                                            \
        ha[arow * 168 + 128 + acol] = (short)hi;                                  \
        ha[arow * 168 + 144 + acol] = (short)f2bf(aWR - bf2f(hi));                \
    }                                                                             \
    BAR();                                                                        \
} while (0)

    for (int t = 0; t < T_STEPS; t += 2) {
        RSTEP(t,     zA, gA, zB, gB, aA, aB);
        RSTEP(t + 1, zB, gB, zA, gA, aB, aA);
    }
#undef RSTEP

    #pragma unroll
    for (int r = 0; r < 4; ++r)
        hfin[(b0 + rgrp + r) * 64 + n] = hlast[r];
}

extern "C" void kernel_launch(void* const* d_in, const int* in_sizes, int n_in,
                              void* d_out, int out_size, void* d_ws, size_t ws_size,
                              hipStream_t stream) {
    const float* x   = (const float*)d_in[0];
    const float* h0  = (const float*)d_in[1];
    const float* g   = (const float*)d_in[2];
    const float* a   = (const float*)d_in[3];
    const float* Wc1 = (const float*)d_in[4];
    const float* bc1 = (const float*)d_in[5];
    const float* Wc2 = (const float*)d_in[6];
    const float* bc2 = (const float*)d_in[7];
    const float* Wp1 = (const float*)d_in[8];
    const float* bp1 = (const float*)d_in[9];
    const float* Wp2 = (const float*)d_in[10];
    const float* bp2 = (const float*)d_in[11];

    float* outs = (float*)d_out;
    float* hfin = outs + (long)T_STEPS * BATCH * HDIM;
    float* capt = hfin + (long)BATCH * HDIM;

    capture_mfma<<<(T_STEPS * BATCH) / 64, 256, 0, stream>>>(x, Wc1, bc1, Wc2, bc2, capt);
    recur_mfma<<<BATCH / 16, 256, 0, stream>>>(h0, g, a, Wp1, bp1, Wp2, bp2, capt, outs, hfin);
}